// Round 4
// baseline (327.647 us; speedup 1.0000x reference)
//
#include <hip/hip_runtime.h>

// entmax-1.5 over rows of an 8192 x 4096 fp32 matrix, boolean mask (int32).
// One wave per row; 64 elements per lane stored as 32 packed-fp16 pairs in
// VGPRs (R2 post-mortem: fp32 z[64] forced AGPR traffic + 2 waves/SIMD ->
// latency-bound). tau* solves g(tau) = sum(relu(z-tau)^2) - 1 = 0 by Newton
// from tau0 = max(z) - 1 (convex decreasing g => global monotone convergence;
// |g'| >= 2 near the root). Sweeps use v_pk_max_f16 + v_dot2_f32_f16 (fp32
// accumulate). fp16 quantization of z costs ~2e-3 absmax vs 2e-2 threshold.

typedef _Float16 h2 __attribute__((ext_vector_type(2)));

constexpr int NROWS = 8192;
constexpr int NCOL  = 4096;
constexpr int PAIRS = 32;   // packed fp16 pairs per lane (64 elems)
constexpr int CHUNK = 16;   // float4/int4 chunks per lane
constexpr int MAXIT = 12;   // Newton cap; early-exit typically ~5-6

static __device__ __forceinline__ h2 pkrtz(float a, float b) {
    // v_cvt_pkrtz_f16_f32 returns __fp16x2; bit-identical to h2.
    return __builtin_bit_cast(h2, __builtin_amdgcn_cvt_pkrtz(a, b));
}

static __device__ __forceinline__ float dot2acc(h2 a, h2 b, float c) {
#if __has_builtin(__builtin_amdgcn_fdot2)
    return __builtin_amdgcn_fdot2(a, b, c, false);   // v_dot2_f32_f16
#else
    return c + (float)a[0] * (float)b[0] + (float)a[1] * (float)b[1];
#endif
}

__global__ __launch_bounds__(256, 6)
void entmax15_kernel(const float* __restrict__ scores,
                     const int*   __restrict__ mask,
                     float*       __restrict__ out)
{
    const int lane = threadIdx.x & 63;
    const int wave = threadIdx.x >> 6;          // 4 waves per block = 4 rows
    const int row  = (blockIdx.x << 2) | wave;  // grid = 2048 -> rows 0..8191

    const float* srow = scores + (size_t)row * NCOL;
    const int*   mrow = mask   + (size_t)row * NCOL;
    float*       orow = out    + (size_t)row * NCOL;

    h2 y[PAIRS];
    float mx = -1e30f;

    // Coalesced float4/int4 loads; pack to fp16 pairs, track fp32 row max.
    #pragma unroll
    for (int c = 0; c < CHUNK; ++c) {
        const int base = c * 256 + lane * 4;
        const float4 s4 = *reinterpret_cast<const float4*>(srow + base);
        const int4   m4 = *reinterpret_cast<const int4*>(mrow + base);
        const float z0 = m4.x ? s4.x * 0.5f : -5000.0f;  // where(mask, s/2, -5000)
        const float z1 = m4.y ? s4.y * 0.5f : -5000.0f;
        const float z2 = m4.z ? s4.z * 0.5f : -5000.0f;
        const float z3 = m4.w ? s4.w * 0.5f : -5000.0f;
        mx = fmaxf(mx, fmaxf(fmaxf(z0, z1), fmaxf(z2, z3)));
        y[c * 2 + 0] = pkrtz(z0, z1);
        y[c * 2 + 1] = pkrtz(z2, z3);
    }

    // Row max across the wave (butterfly; result uniform in all lanes).
    #pragma unroll
    for (int off = 1; off < 64; off <<= 1)
        mx = fmaxf(mx, __shfl_xor(mx, off, 64));

    // Newton. g convex & decreasing => converges from either side; start at
    // mx-1 (left bracket up to fp16 rounding). s1 >= ~1 near root: no div0.
    float t = mx - 1.0f;
    #pragma unroll 1
    for (int it = 0; it < MAXIT; ++it) {
        const _Float16 th = (_Float16)t;
        const h2 t2   = {th, th};
        const h2 zero = {(_Float16)0.f, (_Float16)0.f};
        const h2 one2 = {(_Float16)1.f, (_Float16)1.f};
        float s2a = 0.f, s2b = 0.f, s1a = 0.f, s1b = 0.f;
        #pragma unroll
        for (int i = 0; i < PAIRS; i += 2) {
            const h2 d0 = __builtin_elementwise_max(y[i]     - t2, zero);
            const h2 d1 = __builtin_elementwise_max(y[i + 1] - t2, zero);
            s2a = dot2acc(d0, d0, s2a);   // sum d^2 (fp32 acc)
            s1a = dot2acc(d0, one2, s1a); // sum d   (fp32 acc)
            s2b = dot2acc(d1, d1, s2b);
            s1b = dot2acc(d1, one2, s1b);
        }
        float s2 = s2a + s2b;
        float s1 = s1a + s1b;
        #pragma unroll
        for (int off = 1; off < 64; off <<= 1) {
            s2 += __shfl_xor(s2, off, 64);
            s1 += __shfl_xor(s1, off, 64);
        }
        const float step = (s2 - 1.0f) / (2.0f * s1);
        t += step;
        if (__builtin_fabsf(step) < 1e-4f) break;  // wave-uniform; below fp16 ulp of t
    }

    // Epilogue in fp32: p = relu(z - tau)^2, coalesced float4 stores.
    #pragma unroll
    for (int c = 0; c < CHUNK; ++c) {
        const int base = c * 256 + lane * 4;
        const float v0 = (float)y[c * 2 + 0][0];
        const float v1 = (float)y[c * 2 + 0][1];
        const float v2 = (float)y[c * 2 + 1][0];
        const float v3 = (float)y[c * 2 + 1][1];
        float4 o;
        float d;
        d = fmaxf(v0 - t, 0.f); o.x = d * d;
        d = fmaxf(v1 - t, 0.f); o.y = d * d;
        d = fmaxf(v2 - t, 0.f); o.z = d * d;
        d = fmaxf(v3 - t, 0.f); o.w = d * d;
        *reinterpret_cast<float4*>(orow + base) = o;
    }
}

extern "C" void kernel_launch(void* const* d_in, const int* in_sizes, int n_in,
                              void* d_out, int out_size, void* d_ws, size_t ws_size,
                              hipStream_t stream)
{
    const float* scores = (const float*)d_in[0];
    const int*   mask   = (const int*)d_in[1];
    float*       out    = (float*)d_out;

    dim3 grid(NROWS / 4);   // 4 rows (waves) per 256-thread block
    dim3 block(256);
    hipLaunchKernelGGL(entmax15_kernel, grid, block, 0, stream,
                       scores, mask, out);
}